// Round 1
// baseline (2622.804 us; speedup 1.0000x reference)
//
#include <hip/hip_runtime.h>
#include <stdint.h>

#define B_ 256
#define P_ 620
#define C_ 512
#define T_ 32
#define V_ 140
#define H_ 256
#define A_ 256
#define KC 672   // padded concat K: 140(x) + 256(ctx) + 256(h) = 652 -> 672 = 21*32
#define LOG2E 1.4426950408889634f

typedef unsigned short u16;
typedef __attribute__((ext_vector_type(8))) short bf16x8;
typedef __attribute__((ext_vector_type(4))) float f32x4;

__device__ __forceinline__ float bf2f(u16 u) {
  union { unsigned int i; float f; } v; v.i = ((unsigned int)u) << 16; return v.f;
}
__device__ __forceinline__ float bfu_lo(unsigned int u) {
  union { unsigned int i; float f; } v; v.i = u << 16; return v.f;
}
__device__ __forceinline__ float bfu_hi(unsigned int u) {
  union { unsigned int i; float f; } v; v.i = u & 0xffff0000u; return v.f;
}
__device__ __forceinline__ u16 f2bf(float f) {
  union { float f; unsigned int i; } v; v.f = f;
  unsigned int x = v.i;
  return (u16)((x + 0x7fffu + ((x >> 16) & 1u)) >> 16);
}
__device__ __forceinline__ float sigf(float x) {
  return 1.f / (1.f + __builtin_exp2f(-x * LOG2E));
}
__device__ __forceinline__ float tanhfast(float x) {
  return 1.f - 2.f / (__builtin_exp2f(2.f * LOG2E * x) + 1.f);
}
// dtype-flexible scalar load (f32 flag is block-uniform)
__device__ __forceinline__ float ld_any(const void* p, size_t idx, int f32) {
  return f32 ? ((const float*)p)[idx] : bf2f(((const u16*)p)[idx]);
}
// dtype-flexible 8-element row chunk -> bf16x8 (off multiple of 8)
__device__ __forceinline__ bf16x8 ld8_any(const void* base, size_t off, int f32) {
  if (f32) {
    const float4* p = (const float4*)((const float*)base + off);
    float4 x = p[0], y = p[1];
    bf16x8 r;
    r[0] = (short)f2bf(x.x); r[1] = (short)f2bf(x.y);
    r[2] = (short)f2bf(x.z); r[3] = (short)f2bf(x.w);
    r[4] = (short)f2bf(y.x); r[5] = (short)f2bf(y.y);
    r[6] = (short)f2bf(y.z); r[7] = (short)f2bf(y.w);
    return r;
  }
  return *(const bf16x8*)((const u16*)base + off);
}

// ---------------- dtype detection: low u16 halves of f32 words are garbage ---
__global__ void k_detect(const unsigned int* __restrict__ img, int* __restrict__ flag) {
  __shared__ int mx[256];
  unsigned int u = img[threadIdx.x];
  mx[threadIdx.x] = (int)((u >> 7) & 0xffu);  // bf16 exponent of LOW u16
  __syncthreads();
  if (threadIdx.x == 0) {
    int m = 0;
    #pragma unroll 16
    for (int i = 0; i < 256; i++) m = (mx[i] > m) ? mx[i] : m;
    *flag = (m >= 0x90) ? 1 : 0;  // bf16 N(0,1) data never reaches 2^17
  }
}

// ---------------- init: k-chunk-major W_t, biases, weight conversion ---------
// W_t layout: for kk in [0,84), row jq in [0,1024), e in [0,8):
//   W_t[kk*8192 + jq*8 + e] = W_cat[jq][kk*8+e]
// where W_cat row jq = j*4+q <-> orig gate row n = q*256+j ; cols [W_ih|W_hh|0]
__global__ void k_init(const void* __restrict__ W_ih, const void* __restrict__ W_hh,
                       const void* __restrict__ b_ih, const void* __restrict__ b_hh,
                       const void* __restrict__ Hc_w, const void* __restrict__ Hc_b,
                       const void* __restrict__ Cd_w, const void* __restrict__ Cd_b,
                       u16* __restrict__ W_t, float* __restrict__ bias_cat,
                       u16* __restrict__ Hc_wb, float* __restrict__ hcb_f,
                       u16* __restrict__ Cd_wb, float* __restrict__ cdb_f,
                       const int* __restrict__ flag) {
  const int f32 = *flag;
  const int tid = blockIdx.x * blockDim.x + threadIdx.x;
  const int nthr = gridDim.x * blockDim.x;
  for (int idx = tid; idx < 1024 * KC; idx += nthr) {
    int jq = idx / KC, k = idx - jq * KC;
    int j = jq >> 2, q = jq & 3, n = q * H_ + j;
    u16 v = 0;
    if (k < 396) v = f2bf(ld_any(W_ih, (size_t)n * 396 + k, f32));
    else if (k < 652) v = f2bf(ld_any(W_hh, (size_t)n * H_ + (k - 396), f32));
    W_t[(size_t)(k >> 3) * 8192 + jq * 8 + (k & 7)] = v;
  }
  for (int n = tid; n < 1024; n += nthr) {
    int j = n >> 2, q = n & 3, on = q * H_ + j;
    bias_cat[n] = ld_any(b_ih, on, f32) + ld_any(b_hh, on, f32);
  }
  for (int idx = tid; idx < H_ * A_; idx += nthr) Hc_wb[idx] = f2bf(ld_any(Hc_w, idx, f32));
  for (int idx = tid; idx < V_ * H_; idx += nthr) Cd_wb[idx] = f2bf(ld_any(Cd_w, idx, f32));
  for (int n = tid; n < A_; n += nthr) hcb_f[n] = ld_any(Hc_b, n, f32);
  for (int n = tid; n < V_; n += nthr) cdb_f[n] = ld_any(Cd_b, n, f32);
}

// ---------------- phase 1: attn_img = img @ Ic_w^T + Ic_b (bf16 out) ---------
__global__ __launch_bounds__(256) void k_proj(const void* __restrict__ img,
                                              const void* __restrict__ Ic_w,
                                              const void* __restrict__ Ic_b,
                                              u16* __restrict__ attn_img,
                                              const int* __restrict__ flag) {
  __shared__ __align__(16) short As[128 * 32];
  __shared__ __align__(16) short Bs[128 * 32];
  const int f32 = *flag;
  const int tid = threadIdx.x;
  const int lane = tid & 63, w = tid >> 6;
  const int m0 = blockIdx.x * 128;
  const int n0 = blockIdx.y * 128;
  f32x4 acc[4][4] = {};
  const int wm = w & 1, wn = w >> 1;
  const int fr = lane & 15, fq = lane >> 4;
  const int srow = tid >> 2, scol = (tid & 3) * 8;
  for (int kt = 0; kt < C_; kt += 32) {
    // register-roundtrip staging (prefetch before barrier)
    bf16x8 a0 = ld8_any(img, (size_t)(m0 + srow) * C_ + kt + scol, f32);
    bf16x8 a1 = ld8_any(img, (size_t)(m0 + srow + 64) * C_ + kt + scol, f32);
    bf16x8 b0 = ld8_any(Ic_w, (size_t)(n0 + srow) * C_ + kt + scol, f32);
    bf16x8 b1 = ld8_any(Ic_w, (size_t)(n0 + srow + 64) * C_ + kt + scol, f32);
    __syncthreads();  // previous iteration's fragment reads complete
    *(bf16x8*)(As + tid * 8) = a0;
    *(bf16x8*)(As + (tid + 256) * 8) = a1;
    *(bf16x8*)(Bs + tid * 8) = b0;
    *(bf16x8*)(Bs + (tid + 256) * 8) = b1;
    __syncthreads();
    bf16x8 af[4], bfr[4];
    #pragma unroll
    for (int i = 0; i < 4; i++)
      af[i] = *(const bf16x8*)(As + (wm * 64 + i * 16 + fr) * 32 + fq * 8);
    #pragma unroll
    for (int j = 0; j < 4; j++)
      bfr[j] = *(const bf16x8*)(Bs + (wn * 64 + j * 16 + fr) * 32 + fq * 8);
    #pragma unroll
    for (int i = 0; i < 4; i++)
      #pragma unroll
      for (int j = 0; j < 4; j++)
        acc[i][j] = __builtin_amdgcn_mfma_f32_16x16x32_bf16(af[i], bfr[j], acc[i][j], 0, 0, 0);
  }
  #pragma unroll
  for (int i = 0; i < 4; i++) {
    #pragma unroll
    for (int j = 0; j < 4; j++) {
      const int col = n0 + wn * 64 + j * 16 + fr;
      const float bias = ld_any(Ic_b, col, f32);
      #pragma unroll
      for (int rr = 0; rr < 4; rr++) {
        const int row = m0 + wm * 64 + i * 16 + fq * 4 + rr;
        attn_img[(size_t)row * A_ + col] = f2bf(acc[i][j][rr] + bias);
      }
    }
  }
}

// ---------------- persistent recurrence: whole T-loop, one block per batch ---
__global__ __launch_bounds__(512) void k_seq(
    const u16* __restrict__ Hc_wb, const float* __restrict__ hcb_f,
    const u16* __restrict__ Cd_wb, const float* __restrict__ cdb_f,
    const u16* __restrict__ W_t, const float* __restrict__ bias_cat,
    const u16* __restrict__ attn_img, const void* __restrict__ targets,
    void* __restrict__ d_out, const int* __restrict__ flag) {
  __shared__ float h_s[H_];
  __shared__ float q_s[A_];
  __shared__ __align__(16) float inp_s[KC];   // [x(140) | ctx(256) | h(256) | 0pad]
  __shared__ __align__(16) float ctx_s[8][A_];
  __shared__ float red_m[8], red_l[8];
  __shared__ __align__(16) float gs[1024];    // gates, indexed by jq = j*4+q
  const int f32 = *flag;
  const int b = blockIdx.x;
  const int tid = threadIdx.x;
  const int lane = tid & 63, w = tid >> 6;

  // state init: h = 0, c = 0, x0 = targets[b,0,:], pad = 0
  if (tid < H_) h_s[tid] = 0.f;
  for (int i = tid; i < KC; i += 512) inp_s[i] = 0.f;
  if (tid < V_) inp_s[tid] = ld_any(targets, (size_t)b * T_ * V_ + tid, f32);
  float c_reg = 0.f;  // thread tid<256 owns c[tid]
  const uint4* wt = (const uint4*)W_t + tid * 2;  // rows 2*tid, 2*tid+1
  const float bias0 = bias_cat[2 * tid], bias1 = bias_cat[2 * tid + 1];
  __syncthreads();

  for (int t = 0; t < T_; t++) {
    // ---- phase a: q = h @ Hc_w^T + b ; out_{t-1} = h @ Cd_w^T + b (x_t) ----
    if (tid < A_) {
      float acc = hcb_f[tid];
      const uint2* wr = (const uint2*)(Hc_wb + tid * H_);
      #pragma unroll 8
      for (int j = 0; j < H_ / 4; j++) {
        uint2 u = wr[j];
        acc += bfu_lo(u.x) * h_s[4 * j] + bfu_hi(u.x) * h_s[4 * j + 1]
             + bfu_lo(u.y) * h_s[4 * j + 2] + bfu_hi(u.y) * h_s[4 * j + 3];
      }
      q_s[tid] = acc;
    } else if (t > 0 && tid < A_ + V_) {
      const int v = tid - A_;
      float acc = cdb_f[v];
      const uint2* wr = (const uint2*)(Cd_wb + v * H_);
      #pragma unroll 8
      for (int j = 0; j < H_ / 4; j++) {
        uint2 u = wr[j];
        acc += bfu_lo(u.x) * h_s[4 * j] + bfu_hi(u.x) * h_s[4 * j + 1]
             + bfu_lo(u.y) * h_s[4 * j + 2] + bfu_hi(u.y) * h_s[4 * j + 3];
      }
      const size_t oo = (size_t)b * T_ * V_ + (size_t)(t - 1) * V_ + v;
      if (f32) ((float*)d_out)[oo] = acc;
      else ((u16*)d_out)[oo] = f2bf(acc);
      inp_s[v] = acc;  // x_t = out_{t-1}
    }
    __syncthreads();

    // ---- phase b: online-softmax attention, ctx -> inp_s[140..395] ----
    {
      const float q0 = q_s[lane * 4 + 0], q1 = q_s[lane * 4 + 1];
      const float q2 = q_s[lane * 4 + 2], q3 = q_s[lane * 4 + 3];
      const uint2* ap = (const uint2*)(attn_img + (size_t)b * P_ * A_);
      const float sc = 0.0625f * LOG2E;  // 1/sqrt(A) folded with log2(e)

      float m0v = -3.0e38f, l0 = 0.f, a0 = 0.f, a1 = 0.f, a2 = 0.f, a3 = 0.f;
      float m1v = -3.0e38f, l1 = 0.f, b0 = 0.f, b1 = 0.f, b2 = 0.f, b3 = 0.f;

      for (int p = w; p < P_; p += 16) {
        const int p2 = p + 8;
        const int p2c = (p2 < P_) ? p2 : (P_ - 1);
        uint2 u = ap[p * 64 + lane];
        uint2 u2 = ap[p2c * 64 + lane];
        {
          float v0 = bfu_lo(u.x), v1 = bfu_hi(u.x), v2 = bfu_lo(u.y), v3 = bfu_hi(u.y);
          float s = q0 * v0 + q1 * v1 + q2 * v2 + q3 * v3;
          s += __shfl_xor(s, 32); s += __shfl_xor(s, 16); s += __shfl_xor(s, 8);
          s += __shfl_xor(s, 4);  s += __shfl_xor(s, 2);  s += __shfl_xor(s, 1);
          s *= sc;
          float mn = fmaxf(m0v, s);
          float al = __builtin_exp2f(m0v - mn);
          float es = __builtin_exp2f(s - mn);
          l0 = l0 * al + es;
          a0 = a0 * al + es * v0; a1 = a1 * al + es * v1;
          a2 = a2 * al + es * v2; a3 = a3 * al + es * v3;
          m0v = mn;
        }
        {
          float v0 = bfu_lo(u2.x), v1 = bfu_hi(u2.x), v2 = bfu_lo(u2.y), v3 = bfu_hi(u2.y);
          float s = q0 * v0 + q1 * v1 + q2 * v2 + q3 * v3;
          s += __shfl_xor(s, 32); s += __shfl_xor(s, 16); s += __shfl_xor(s, 8);
          s += __shfl_xor(s, 4);  s += __shfl_xor(s, 2);  s += __shfl_xor(s, 1);
          s *= sc;
          if (p2 >= P_) s = -3.0e38f;   // mask tail (m1v already finite here)
          float mn = fmaxf(m1v, s);
          float al = __builtin_exp2f(m1v - mn);
          float es = __builtin_exp2f(s - mn);
          l1 = l1 * al + es;
          b0 = b0 * al + es * v0; b1 = b1 * al + es * v1;
          b2 = b2 * al + es * v2; b3 = b3 * al + es * v3;
          m1v = mn;
        }
      }
      // merge the two chains
      float mw = fmaxf(m0v, m1v);
      float e0 = __builtin_exp2f(m0v - mw), e1 = __builtin_exp2f(m1v - mw);
      float lw = l0 * e0 + l1 * e1;
      float c0 = a0 * e0 + b0 * e1, c1 = a1 * e0 + b1 * e1;
      float c2 = a2 * e0 + b2 * e1, c3 = a3 * e0 + b3 * e1;

      ((float4*)ctx_s[w])[lane] = make_float4(c0, c1, c2, c3);
      if (lane == 0) { red_m[w] = mw; red_l[w] = lw; }
    }
    __syncthreads();
    if (tid < A_) {
      float mt = red_m[0];
      #pragma unroll
      for (int i = 1; i < 8; i++) mt = fmaxf(mt, red_m[i]);
      float lt = 0.f, acc = 0.f;
      #pragma unroll
      for (int i = 0; i < 8; i++) {
        float bw = __builtin_exp2f(red_m[i] - mt);
        lt += red_l[i] * bw;
        acc += ctx_s[i][tid] * bw;
      }
      inp_s[V_ + tid] = acc / lt;
    }
    __syncthreads();

    // ---- phase c: gates GEMV, thread owns permuted rows 2*tid, 2*tid+1 ----
    {
      float acc0 = bias0, acc1 = bias1;
      #pragma unroll 4
      for (int kk = 0; kk < KC / 8; kk++) {
        const uint4 u0 = wt[kk * 1024];
        const uint4 u1 = wt[kk * 1024 + 1];
        const float4 i0 = *(const float4*)(inp_s + kk * 8);
        const float4 i1 = *(const float4*)(inp_s + kk * 8 + 4);
        acc0 += bfu_lo(u0.x) * i0.x + bfu_hi(u0.x) * i0.y
              + bfu_lo(u0.y) * i0.z + bfu_hi(u0.y) * i0.w
              + bfu_lo(u0.z) * i1.x + bfu_hi(u0.z) * i1.y
              + bfu_lo(u0.w) * i1.z + bfu_hi(u0.w) * i1.w;
        acc1 += bfu_lo(u1.x) * i0.x + bfu_hi(u1.x) * i0.y
              + bfu_lo(u1.y) * i0.z + bfu_hi(u1.y) * i0.w
              + bfu_lo(u1.z) * i1.x + bfu_hi(u1.z) * i1.y
              + bfu_lo(u1.w) * i1.z + bfu_hi(u1.w) * i1.w;
      }
      gs[2 * tid] = acc0;
      gs[2 * tid + 1] = acc1;
    }
    __syncthreads();

    // ---- phase d: LSTM cell, thread tid<256 owns hidden j = tid ----
    if (tid < H_) {
      const float4 g4 = *(const float4*)(gs + 4 * tid);  // [i,f,g,o] for j=tid
      const float is = sigf(g4.x), fs = sigf(g4.y);
      const float gt = tanhfast(g4.z), os = sigf(g4.w);
      const float cn = fs * c_reg + is * gt;
      const float h2 = os * tanhfast(cn);
      c_reg = cn;
      h_s[tid] = h2;
      inp_s[V_ + A_ + tid] = h2;
    }
    __syncthreads();
  }

  // ---- final out for t = T-1 ----
  if (tid < V_) {
    float acc = cdb_f[tid];
    const uint2* wr = (const uint2*)(Cd_wb + tid * H_);
    #pragma unroll 8
    for (int j = 0; j < H_ / 4; j++) {
      uint2 u = wr[j];
      acc += bfu_lo(u.x) * h_s[4 * j] + bfu_hi(u.x) * h_s[4 * j + 1]
           + bfu_lo(u.y) * h_s[4 * j + 2] + bfu_hi(u.y) * h_s[4 * j + 3];
    }
    const size_t oo = (size_t)b * T_ * V_ + (size_t)(T_ - 1) * V_ + tid;
    if (f32) ((float*)d_out)[oo] = acc;
    else ((u16*)d_out)[oo] = f2bf(acc);
  }
}

extern "C" void kernel_launch(void* const* d_in, const int* in_sizes, int n_in,
                              void* d_out, int out_size, void* d_ws, size_t ws_size,
                              hipStream_t stream) {
  (void)in_sizes; (void)n_in; (void)out_size; (void)ws_size;
  const void* img  = d_in[0];
  const void* tgt  = d_in[1];
  const void* Ic_w = d_in[2];
  const void* Ic_b = d_in[3];
  const void* Hc_w = d_in[4];
  const void* Hc_b = d_in[5];
  const void* W_ih = d_in[6];
  const void* W_hh = d_in[7];
  const void* b_ih = d_in[8];
  const void* b_hh = d_in[9];
  const void* Cd_w = d_in[10];
  const void* Cd_b = d_in[11];

  char* ws = (char*)d_ws;
  size_t off = 0;
  auto alloc = [&](size_t bytes) -> void* {
    void* p = ws + off;
    off += (bytes + 255) & ~(size_t)255;
    return p;
  };
  u16*   attn_img = (u16*)alloc((size_t)B_ * P_ * A_ * 2);
  u16*   W_t      = (u16*)alloc((size_t)1024 * KC * 2);
  float* bias_cat = (float*)alloc(1024 * 4);
  u16*   Hc_wb    = (u16*)alloc((size_t)H_ * A_ * 2);
  float* hcb_f    = (float*)alloc(A_ * 4);
  u16*   Cd_wb    = (u16*)alloc((size_t)V_ * H_ * 2);
  float* cdb_f    = (float*)alloc(V_ * 4);
  int*   flag     = (int*)alloc(256);

  k_detect<<<dim3(1), dim3(256), 0, stream>>>((const unsigned int*)img, flag);
  k_init<<<dim3(512), dim3(256), 0, stream>>>(W_ih, W_hh, b_ih, b_hh,
                                              Hc_w, Hc_b, Cd_w, Cd_b,
                                              W_t, bias_cat,
                                              Hc_wb, hcb_f, Cd_wb, cdb_f, flag);
  k_proj<<<dim3(1240, 2), dim3(256), 0, stream>>>(img, Ic_w, Ic_b, attn_img, flag);
  k_seq<<<dim3(B_), dim3(512), 0, stream>>>(Hc_wb, hcb_f, Cd_wb, cdb_f,
                                            W_t, bias_cat, attn_img, tgt, d_out, flag);
}

// Round 2
// 1911.871 us; speedup vs baseline: 1.3719x; 1.3719x over previous
//
#include <hip/hip_runtime.h>
#include <stdint.h>

#define B_ 256
#define P_ 620
#define C_ 512
#define T_ 32
#define V_ 140
#define H_ 256
#define A_ 256
#define KC 672   // padded concat K: 140(x) + 256(ctx) + 256(h) = 652 -> 672 = 21*32
#define LOG2E 1.4426950408889634f

typedef unsigned short u16;
typedef __attribute__((ext_vector_type(8))) short bf16x8;
typedef __attribute__((ext_vector_type(4))) float f32x4;

__device__ __forceinline__ float bf2f(u16 u) {
  union { unsigned int i; float f; } v; v.i = ((unsigned int)u) << 16; return v.f;
}
__device__ __forceinline__ float bfu_lo(unsigned int u) {
  union { unsigned int i; float f; } v; v.i = u << 16; return v.f;
}
__device__ __forceinline__ float bfu_hi(unsigned int u) {
  union { unsigned int i; float f; } v; v.i = u & 0xffff0000u; return v.f;
}
__device__ __forceinline__ u16 f2bf(float f) {
  union { float f; unsigned int i; } v; v.f = f;
  unsigned int x = v.i;
  return (u16)((x + 0x7fffu + ((x >> 16) & 1u)) >> 16);
}
__device__ __forceinline__ float sigf(float x) {
  return 1.f / (1.f + __builtin_exp2f(-x * LOG2E));
}
__device__ __forceinline__ float tanhfast(float x) {
  return 1.f - 2.f / (__builtin_exp2f(2.f * LOG2E * x) + 1.f);
}
__device__ __forceinline__ float ld_any(const void* p, size_t idx, int f32) {
  return f32 ? ((const float*)p)[idx] : bf2f(((const u16*)p)[idx]);
}
__device__ __forceinline__ bf16x8 ld8_any(const void* base, size_t off, int f32) {
  if (f32) {
    const float4* p = (const float4*)((const float*)base + off);
    float4 x = p[0], y = p[1];
    bf16x8 r;
    r[0] = (short)f2bf(x.x); r[1] = (short)f2bf(x.y);
    r[2] = (short)f2bf(x.z); r[3] = (short)f2bf(x.w);
    r[4] = (short)f2bf(y.x); r[5] = (short)f2bf(y.y);
    r[6] = (short)f2bf(y.z); r[7] = (short)f2bf(y.w);
    return r;
  }
  return *(const bf16x8*)((const u16*)base + off);
}
// dot of 8 bf16 weights (uint4) against 8 f32 inputs (two float4)
__device__ __forceinline__ float dot8(uint4 u, float4 iA, float4 iB) {
  return bfu_lo(u.x) * iA.x + bfu_hi(u.x) * iA.y
       + bfu_lo(u.y) * iA.z + bfu_hi(u.y) * iA.w
       + bfu_lo(u.z) * iB.x + bfu_hi(u.z) * iB.y
       + bfu_lo(u.w) * iB.z + bfu_hi(u.w) * iB.w;
}

// ---------------- dtype detection: low u16 halves of f32 words are garbage ---
__global__ void k_detect(const unsigned int* __restrict__ img, int* __restrict__ flag) {
  __shared__ int mx[256];
  unsigned int u = img[threadIdx.x];
  mx[threadIdx.x] = (int)((u >> 7) & 0xffu);  // bf16 exponent of LOW u16
  __syncthreads();
  if (threadIdx.x == 0) {
    int m = 0;
    #pragma unroll 16
    for (int i = 0; i < 256; i++) m = (mx[i] > m) ? mx[i] : m;
    *flag = (m >= 0x90) ? 1 : 0;  // bf16 N(0,1) data never reaches 2^17
  }
}

// ---------------- init: k-chunk-major W_t, biases, weight conversion ---------
// W_t[kk*8192 + jq*8 + e] = W_cat[jq][kk*8+e],  jq = j*4+q <-> gate row q*256+j
__global__ void k_init(const void* __restrict__ W_ih, const void* __restrict__ W_hh,
                       const void* __restrict__ b_ih, const void* __restrict__ b_hh,
                       const void* __restrict__ Hc_w, const void* __restrict__ Hc_b,
                       const void* __restrict__ Cd_w, const void* __restrict__ Cd_b,
                       u16* __restrict__ W_t, float* __restrict__ bias_cat,
                       u16* __restrict__ Hc_wb, float* __restrict__ hcb_f,
                       u16* __restrict__ Cd_wb, float* __restrict__ cdb_f,
                       const int* __restrict__ flag) {
  const int f32 = *flag;
  const int tid = blockIdx.x * blockDim.x + threadIdx.x;
  const int nthr = gridDim.x * blockDim.x;
  for (int idx = tid; idx < 1024 * KC; idx += nthr) {
    int jq = idx / KC, k = idx - jq * KC;
    int j = jq >> 2, q = jq & 3, n = q * H_ + j;
    u16 v = 0;
    if (k < 396) v = f2bf(ld_any(W_ih, (size_t)n * 396 + k, f32));
    else if (k < 652) v = f2bf(ld_any(W_hh, (size_t)n * H_ + (k - 396), f32));
    W_t[(size_t)(k >> 3) * 8192 + jq * 8 + (k & 7)] = v;
  }
  for (int n = tid; n < 1024; n += nthr) {
    int j = n >> 2, q = n & 3, on = q * H_ + j;
    bias_cat[n] = ld_any(b_ih, on, f32) + ld_any(b_hh, on, f32);
  }
  for (int idx = tid; idx < H_ * A_; idx += nthr) Hc_wb[idx] = f2bf(ld_any(Hc_w, idx, f32));
  for (int idx = tid; idx < V_ * H_; idx += nthr) Cd_wb[idx] = f2bf(ld_any(Cd_w, idx, f32));
  for (int n = tid; n < A_; n += nthr) hcb_f[n] = ld_any(Hc_b, n, f32);
  for (int n = tid; n < V_; n += nthr) cdb_f[n] = ld_any(Cd_b, n, f32);
}

// ---------------- phase 1: attn_img = img @ Ic_w^T + Ic_b (bf16 out) ---------
// grid: 2480 1-D; swizzled so (m, n=0) and (m, n=1) are 8 apart -> same XCD L2
__global__ __launch_bounds__(256) void k_proj(const void* __restrict__ img,
                                              const void* __restrict__ Ic_w,
                                              const void* __restrict__ Ic_b,
                                              u16* __restrict__ attn_img,
                                              const int* __restrict__ flag) {
  __shared__ __align__(16) short As[128 * 32];
  __shared__ __align__(16) short Bs[128 * 32];
  const int f32 = *flag;
  const int tid = threadIdx.x;
  const int lane = tid & 63, w = tid >> 6;
  const int wg = blockIdx.x;
  const int m0 = ((wg & 7) + (wg >> 4) * 8) * 128;
  const int n0 = ((wg >> 3) & 1) * 128;
  f32x4 acc[4][4] = {};
  const int wm = w & 1, wn = w >> 1;
  const int fr = lane & 15, fq = lane >> 4;
  const int srow = tid >> 2, scol = (tid & 3) * 8;
  for (int kt = 0; kt < C_; kt += 32) {
    bf16x8 a0 = ld8_any(img, (size_t)(m0 + srow) * C_ + kt + scol, f32);
    bf16x8 a1 = ld8_any(img, (size_t)(m0 + srow + 64) * C_ + kt + scol, f32);
    bf16x8 b0 = ld8_any(Ic_w, (size_t)(n0 + srow) * C_ + kt + scol, f32);
    bf16x8 b1 = ld8_any(Ic_w, (size_t)(n0 + srow + 64) * C_ + kt + scol, f32);
    __syncthreads();
    *(bf16x8*)(As + tid * 8) = a0;
    *(bf16x8*)(As + (tid + 256) * 8) = a1;
    *(bf16x8*)(Bs + tid * 8) = b0;
    *(bf16x8*)(Bs + (tid + 256) * 8) = b1;
    __syncthreads();
    bf16x8 af[4], bfr[4];
    #pragma unroll
    for (int i = 0; i < 4; i++)
      af[i] = *(const bf16x8*)(As + (wm * 64 + i * 16 + fr) * 32 + fq * 8);
    #pragma unroll
    for (int j = 0; j < 4; j++)
      bfr[j] = *(const bf16x8*)(Bs + (wn * 64 + j * 16 + fr) * 32 + fq * 8);
    #pragma unroll
    for (int i = 0; i < 4; i++)
      #pragma unroll
      for (int j = 0; j < 4; j++)
        acc[i][j] = __builtin_amdgcn_mfma_f32_16x16x32_bf16(af[i], bfr[j], acc[i][j], 0, 0, 0);
  }
  #pragma unroll
  for (int i = 0; i < 4; i++) {
    #pragma unroll
    for (int j = 0; j < 4; j++) {
      const int col = n0 + wn * 64 + j * 16 + fr;
      const float bias = ld_any(Ic_b, col, f32);
      #pragma unroll
      for (int rr = 0; rr < 4; rr++) {
        const int row = m0 + wm * 64 + i * 16 + fq * 4 + rr;
        attn_img[(size_t)row * A_ + col] = f2bf(acc[i][j][rr] + bias);
      }
    }
  }
}

// ---------------- persistent recurrence: one block per batch, wave-specialized
// per step: P1 {q,out GEMV} | P2 {waves0-3: attention (fixed-offset softmax),
//           waves4-7: gates xh-partial} | P3 {ctx finalize; gates ctx-part} | cell
__global__ __launch_bounds__(512) void k_seq(
    const u16* __restrict__ Hc_wb, const float* __restrict__ hcb_f,
    const u16* __restrict__ Cd_wb, const float* __restrict__ cdb_f,
    const u16* __restrict__ W_t, const float* __restrict__ bias_cat,
    const u16* __restrict__ attn_img, const void* __restrict__ targets,
    void* __restrict__ d_out, const int* __restrict__ flag) {
  __shared__ float h_s[H_];
  __shared__ float q_s[A_];
  __shared__ __align__(16) float inp_s[KC];   // [x(140) | ctx(256) | h(256) | 0pad]
  __shared__ __align__(16) float ctx_s[4][A_];
  __shared__ float red_l[4];
  __shared__ __align__(16) float gpart[1024]; // permuted gate accum, row jq=j*4+q
  const int f32 = *flag;
  const int b = blockIdx.x;
  const int tid = threadIdx.x;
  const int lane = tid & 63, w = tid >> 6;

  if (tid < H_) h_s[tid] = 0.f;
  for (int i = tid; i < KC; i += 512) inp_s[i] = 0.f;
  if (tid < V_) inp_s[tid] = ld_any(targets, (size_t)b * T_ * V_ + tid, f32);
  float c_reg = 0.f;                          // thread tid<256 owns c[tid]
  float4 bias4 = make_float4(0.f, 0.f, 0.f, 0.f);
  if (tid >= 256) bias4 = *(const float4*)(bias_cat + 4 * (tid - 256));
  const float sc = 0.0625f * LOG2E;           // 1/sqrt(A) folded with log2(e)
  __syncthreads();

  for (int t = 0; t < T_; t++) {
    // ---- P1: q = h@Hc^T + b (tid<256) ; out_{t-1} = h@Cd^T + b (256..395) ---
    if (tid < A_) {
      float acc = hcb_f[tid];
      const uint2* wr = (const uint2*)(Hc_wb + tid * H_);
      #pragma unroll 8
      for (int j = 0; j < H_ / 4; j++) {
        uint2 u = wr[j];
        acc += bfu_lo(u.x) * h_s[4 * j] + bfu_hi(u.x) * h_s[4 * j + 1]
             + bfu_lo(u.y) * h_s[4 * j + 2] + bfu_hi(u.y) * h_s[4 * j + 3];
      }
      q_s[tid] = acc;
    } else if (t > 0 && tid < A_ + V_) {
      const int v = tid - A_;
      float acc = cdb_f[v];
      const uint2* wr = (const uint2*)(Cd_wb + v * H_);
      #pragma unroll 8
      for (int j = 0; j < H_ / 4; j++) {
        uint2 u = wr[j];
        acc += bfu_lo(u.x) * h_s[4 * j] + bfu_hi(u.x) * h_s[4 * j + 1]
             + bfu_lo(u.y) * h_s[4 * j + 2] + bfu_hi(u.y) * h_s[4 * j + 3];
      }
      const size_t oo = (size_t)b * T_ * V_ + (size_t)(t - 1) * V_ + v;
      if (f32) ((float*)d_out)[oo] = acc;
      else ((u16*)d_out)[oo] = f2bf(acc);
      inp_s[v] = acc;  // x_t = out_{t-1}
    }
    __syncthreads();  // barrier A

    // ---- P2: wave-specialized, no internal barriers ----
    if (w < 4) {
      // attention: 16 lanes/position, 4 positions/wave/iter, 16 waves-groups
      // fixed-offset softmax: scores are tiny (|s*sc*log2e| << 16 by
      // construction: h tanh-bounded, weights ~N(0,0.02^2)); exp2(x-16)
      // cancels exactly after the /l normalize.
      const int l16 = lane & 15, g = lane >> 4;
      float qr[16];
      #pragma unroll
      for (int e = 0; e < 8; e++) {
        qr[e] = q_s[l16 * 8 + e];
        qr[8 + e] = q_s[128 + l16 * 8 + e];
      }
      const uint4* ap = (const uint4*)(attn_img + (size_t)b * P_ * A_);
      const int pbase = w * 4 + g;
      float l_acc = 0.f;
      float cx[16] = {};
      #pragma unroll 3
      for (int it = 0; it < 39; it++) {
        const int p = pbase + it * 16;
        const int pc = (p < P_) ? p : (P_ - 1);
        const uint4 u0 = ap[(size_t)pc * 32 + l16];
        const uint4 u1 = ap[(size_t)pc * 32 + 16 + l16];
        float v[16];
        v[0] = bfu_lo(u0.x); v[1] = bfu_hi(u0.x);
        v[2] = bfu_lo(u0.y); v[3] = bfu_hi(u0.y);
        v[4] = bfu_lo(u0.z); v[5] = bfu_hi(u0.z);
        v[6] = bfu_lo(u0.w); v[7] = bfu_hi(u0.w);
        v[8] = bfu_lo(u1.x); v[9] = bfu_hi(u1.x);
        v[10] = bfu_lo(u1.y); v[11] = bfu_hi(u1.y);
        v[12] = bfu_lo(u1.z); v[13] = bfu_hi(u1.z);
        v[14] = bfu_lo(u1.w); v[15] = bfu_hi(u1.w);
        float s0 = qr[0] * v[0] + qr[1] * v[1] + qr[2] * v[2] + qr[3] * v[3];
        float s1 = qr[4] * v[4] + qr[5] * v[5] + qr[6] * v[6] + qr[7] * v[7];
        float s2 = qr[8] * v[8] + qr[9] * v[9] + qr[10] * v[10] + qr[11] * v[11];
        float s3 = qr[12] * v[12] + qr[13] * v[13] + qr[14] * v[14] + qr[15] * v[15];
        float s = (s0 + s1) + (s2 + s3);
        s += __shfl_xor(s, 1); s += __shfl_xor(s, 2);
        s += __shfl_xor(s, 4); s += __shfl_xor(s, 8);
        const float sl = (p < P_) ? s * sc : -3.0e38f;
        const float es = __builtin_exp2f(sl - 16.f);
        l_acc += es;
        #pragma unroll
        for (int k = 0; k < 16; k++) cx[k] += es * v[k];
      }
      #pragma unroll
      for (int k = 0; k < 16; k++) {
        cx[k] += __shfl_xor(cx[k], 16);
        cx[k] += __shfl_xor(cx[k], 32);
      }
      l_acc += __shfl_xor(l_acc, 16);
      l_acc += __shfl_xor(l_acc, 32);
      if (g == 0) {
        #pragma unroll
        for (int e = 0; e < 8; e++) {
          ctx_s[w][l16 * 8 + e] = cx[e];
          ctx_s[w][128 + l16 * 8 + e] = cx[8 + e];
        }
        if (l16 == 0) red_l[w] = l_acc;
      }
    } else {
      // gates xh-partial: rows 4r..4r+3, chunks 0..16 (x) and 50..83 (h+pad)
      const int r = tid - 256;
      const uint4* wt4 = (const uint4*)W_t + 4 * r;
      float g0 = bias4.x, g1 = bias4.y, g2 = bias4.z, g3 = bias4.w;
      #pragma unroll 2
      for (int kk = 0; kk < 17; kk++) {
        const float4 iA = *(const float4*)(inp_s + kk * 8);
        const float4 iB = *(const float4*)(inp_s + kk * 8 + 4);
        const uint4 u0 = wt4[kk * 1024 + 0];
        const uint4 u1 = wt4[kk * 1024 + 1];
        const uint4 u2 = wt4[kk * 1024 + 2];
        const uint4 u3 = wt4[kk * 1024 + 3];
        g0 += dot8(u0, iA, iB); g1 += dot8(u1, iA, iB);
        g2 += dot8(u2, iA, iB); g3 += dot8(u3, iA, iB);
      }
      #pragma unroll 2
      for (int kk = 50; kk < 84; kk++) {
        const float4 iA = *(const float4*)(inp_s + kk * 8);
        const float4 iB = *(const float4*)(inp_s + kk * 8 + 4);
        const uint4 u0 = wt4[kk * 1024 + 0];
        const uint4 u1 = wt4[kk * 1024 + 1];
        const uint4 u2 = wt4[kk * 1024 + 2];
        const uint4 u3 = wt4[kk * 1024 + 3];
        g0 += dot8(u0, iA, iB); g1 += dot8(u1, iA, iB);
        g2 += dot8(u2, iA, iB); g3 += dot8(u3, iA, iB);
      }
      gpart[4 * r + 0] = g0; gpart[4 * r + 1] = g1;
      gpart[4 * r + 2] = g2; gpart[4 * r + 3] = g3;
    }
    __syncthreads();  // barrier B

    // ---- P3a: finalize ctx -> inp_s[140..395] ----
    if (tid < A_) {
      const float l = red_l[0] + red_l[1] + red_l[2] + red_l[3];
      const float cv = ctx_s[0][tid] + ctx_s[1][tid] + ctx_s[2][tid] + ctx_s[3][tid];
      inp_s[V_ + tid] = cv / l;
    }
    __syncthreads();  // barrier C

    // ---- P3b: gates ctx-part, rows 2*tid..2*tid+1, chunks 17..49 ----
    {
      const int r2 = tid << 1;
      float g0 = gpart[r2], g1 = gpart[r2 + 1];
      const uint4* wt2 = (const uint4*)W_t + r2;
      #pragma unroll 2
      for (int kk = 17; kk < 50; kk++) {
        const float4 iA = *(const float4*)(inp_s + kk * 8);
        const float4 iB = *(const float4*)(inp_s + kk * 8 + 4);
        const uint4 u0 = wt2[kk * 1024];
        const uint4 u1 = wt2[kk * 1024 + 1];
        g0 += dot8(u0, iA, iB);
        g1 += dot8(u1, iA, iB);
      }
      gpart[r2] = g0; gpart[r2 + 1] = g1;
    }
    __syncthreads();  // barrier D

    // ---- cell: thread tid<256 owns hidden j = tid ----
    if (tid < H_) {
      const float4 g4 = *(const float4*)(gpart + 4 * tid);  // [i,f,g,o]
      const float is = sigf(g4.x), fs = sigf(g4.y);
      const float gt = tanhfast(g4.z), os = sigf(g4.w);
      const float cn = fs * c_reg + is * gt;
      const float h2 = os * tanhfast(cn);
      c_reg = cn;
      h_s[tid] = h2;
      inp_s[V_ + A_ + tid] = h2;
    }
    __syncthreads();  // barrier E
  }

  // ---- final out for t = T-1 ----
  if (tid < V_) {
    float acc = cdb_f[tid];
    const uint2* wr = (const uint2*)(Cd_wb + tid * H_);
    #pragma unroll 8
    for (int j = 0; j < H_ / 4; j++) {
      uint2 u = wr[j];
      acc += bfu_lo(u.x) * h_s[4 * j] + bfu_hi(u.x) * h_s[4 * j + 1]
           + bfu_lo(u.y) * h_s[4 * j + 2] + bfu_hi(u.y) * h_s[4 * j + 3];
    }
    const size_t oo = (size_t)b * T_ * V_ + (size_t)(T_ - 1) * V_ + tid;
    if (f32) ((float*)d_out)[oo] = acc;
    else ((u16*)d_out)[oo] = f2bf(acc);
  }
}

extern "C" void kernel_launch(void* const* d_in, const int* in_sizes, int n_in,
                              void* d_out, int out_size, void* d_ws, size_t ws_size,
                              hipStream_t stream) {
  (void)in_sizes; (void)n_in; (void)out_size; (void)ws_size;
  const void* img  = d_in[0];
  const void* tgt  = d_in[1];
  const void* Ic_w = d_in[2];
  const void* Ic_b = d_in[3];
  const void* Hc_w = d_in[4];
  const void* Hc_b = d_in[5];
  const void* W_ih = d_in[6];
  const void* W_hh = d_in[7];
  const void* b_ih = d_in[8];
  const void* b_hh = d_in[9];
  const void* Cd_w = d_in[10];
  const void* Cd_b = d_in[11];

  char* ws = (char*)d_ws;
  size_t off = 0;
  auto alloc = [&](size_t bytes) -> void* {
    void* p = ws + off;
    off += (bytes + 255) & ~(size_t)255;
    return p;
  };
  u16*   attn_img = (u16*)alloc((size_t)B_ * P_ * A_ * 2);
  u16*   W_t      = (u16*)alloc((size_t)1024 * KC * 2);
  float* bias_cat = (float*)alloc(1024 * 4);
  u16*   Hc_wb    = (u16*)alloc((size_t)H_ * A_ * 2);
  float* hcb_f    = (float*)alloc(A_ * 4);
  u16*   Cd_wb    = (u16*)alloc((size_t)V_ * H_ * 2);
  float* cdb_f    = (float*)alloc(V_ * 4);
  int*   flag     = (int*)alloc(256);

  k_detect<<<dim3(1), dim3(256), 0, stream>>>((const unsigned int*)img, flag);
  k_init<<<dim3(512), dim3(256), 0, stream>>>(W_ih, W_hh, b_ih, b_hh,
                                              Hc_w, Hc_b, Cd_w, Cd_b,
                                              W_t, bias_cat,
                                              Hc_wb, hcb_f, Cd_wb, cdb_f, flag);
  k_proj<<<dim3(2480), dim3(256), 0, stream>>>(img, Ic_w, Ic_b, attn_img, flag);
  k_seq<<<dim3(B_), dim3(512), 0, stream>>>(Hc_wb, hcb_f, Cd_wb, cdb_f,
                                            W_t, bias_cat, attn_img, tgt, d_out, flag);
}

// Round 3
// 1729.733 us; speedup vs baseline: 1.5163x; 1.1053x over previous
//
#include <hip/hip_runtime.h>
#include <stdint.h>

#define B_ 256
#define P_ 620
#define C_ 512
#define T_ 32
#define V_ 140
#define H_ 256
#define A_ 256
#define KC 672   // padded concat K: 140(x) + 256(ctx) + 256(h) = 652 -> 672 = 21*32
#define LOG2E 1.4426950408889634f

typedef unsigned short u16;
typedef __attribute__((ext_vector_type(8))) short bf16x8;
typedef __attribute__((ext_vector_type(4))) float f32x4;

__device__ __forceinline__ float bf2f(u16 u) {
  union { unsigned int i; float f; } v; v.i = ((unsigned int)u) << 16; return v.f;
}
__device__ __forceinline__ float bfu_lo(unsigned int u) {
  union { unsigned int i; float f; } v; v.i = u << 16; return v.f;
}
__device__ __forceinline__ float bfu_hi(unsigned int u) {
  union { unsigned int i; float f; } v; v.i = u & 0xffff0000u; return v.f;
}
__device__ __forceinline__ u16 f2bf(float f) {
  union { float f; unsigned int i; } v; v.f = f;
  unsigned int x = v.i;
  return (u16)((x + 0x7fffu + ((x >> 16) & 1u)) >> 16);
}
__device__ __forceinline__ float sigf(float x) {
  return 1.f / (1.f + __builtin_exp2f(-x * LOG2E));
}
__device__ __forceinline__ float tanhfast(float x) {
  return 1.f - 2.f / (__builtin_exp2f(2.f * LOG2E * x) + 1.f);
}
__device__ __forceinline__ float ld_any(const void* p, size_t idx, int f32) {
  return f32 ? ((const float*)p)[idx] : bf2f(((const u16*)p)[idx]);
}
__device__ __forceinline__ bf16x8 ld8_any(const void* base, size_t off, int f32) {
  if (f32) {
    const float4* p = (const float4*)((const float*)base + off);
    float4 x = p[0], y = p[1];
    bf16x8 r;
    r[0] = (short)f2bf(x.x); r[1] = (short)f2bf(x.y);
    r[2] = (short)f2bf(x.z); r[3] = (short)f2bf(x.w);
    r[4] = (short)f2bf(y.x); r[5] = (short)f2bf(y.y);
    r[6] = (short)f2bf(y.z); r[7] = (short)f2bf(y.w);
    return r;
  }
  return *(const bf16x8*)((const u16*)base + off);
}
// dot of 8 bf16 weights (uint4) against 8 f32 inputs (two float4)
__device__ __forceinline__ float dot8(uint4 u, float4 iA, float4 iB) {
  return bfu_lo(u.x) * iA.x + bfu_hi(u.x) * iA.y
       + bfu_lo(u.y) * iA.z + bfu_hi(u.y) * iA.w
       + bfu_lo(u.z) * iB.x + bfu_hi(u.z) * iB.y
       + bfu_lo(u.w) * iB.z + bfu_hi(u.w) * iB.w;
}

// ---------------- dtype detection: low u16 halves of f32 words are garbage ---
__global__ void k_detect(const unsigned int* __restrict__ img, int* __restrict__ flag) {
  __shared__ int mx[256];
  unsigned int u = img[threadIdx.x];
  mx[threadIdx.x] = (int)((u >> 7) & 0xffu);  // bf16 exponent of LOW u16
  __syncthreads();
  if (threadIdx.x == 0) {
    int m = 0;
    #pragma unroll 16
    for (int i = 0; i < 256; i++) m = (mx[i] > m) ? mx[i] : m;
    *flag = (m >= 0x90) ? 1 : 0;  // bf16 N(0,1) data never reaches 2^17
  }
}

// ---------------- init: coalesced weight layouts ----------------------------
// W2[((kk*4 + blk)*256 + r)*8 + e] = W_cat[jq = blk*256+r][kk*8+e]
//   (W_cat row jq = j*4+q <-> orig gate row n = q*256+j ; cols [W_ih|W_hh|0])
// Hc_p[j2*256 + n] = pack(bf16(Hc_w[n][2j2]), bf16(Hc_w[n][2j2+1]))
// Cd_p[j2*140 + v] = pack(bf16(Cd_w[v][2j2]), bf16(Cd_w[v][2j2+1]))
__global__ void k_init(const void* __restrict__ W_ih, const void* __restrict__ W_hh,
                       const void* __restrict__ b_ih, const void* __restrict__ b_hh,
                       const void* __restrict__ Hc_w, const void* __restrict__ Hc_b,
                       const void* __restrict__ Cd_w, const void* __restrict__ Cd_b,
                       u16* __restrict__ W2, float* __restrict__ bias_cat,
                       unsigned int* __restrict__ Hc_p, float* __restrict__ hcb_f,
                       unsigned int* __restrict__ Cd_p, float* __restrict__ cdb_f,
                       const int* __restrict__ flag) {
  const int f32 = *flag;
  const int tid = blockIdx.x * blockDim.x + threadIdx.x;
  const int nthr = gridDim.x * blockDim.x;
  for (int idx = tid; idx < 1024 * KC; idx += nthr) {
    int jq = idx / KC, k = idx - jq * KC;
    int j = jq >> 2, q = jq & 3, n = q * H_ + j;
    u16 v = 0;
    if (k < 396) v = f2bf(ld_any(W_ih, (size_t)n * 396 + k, f32));
    else if (k < 652) v = f2bf(ld_any(W_hh, (size_t)n * H_ + (k - 396), f32));
    const int kk = k >> 3, e = k & 7, blk = jq >> 8, r = jq & 255;
    W2[((size_t)(kk * 4 + blk) * 256 + r) * 8 + e] = v;
  }
  for (int n = tid; n < 1024; n += nthr) {
    int j = n >> 2, q = n & 3, on = q * H_ + j;
    bias_cat[n] = ld_any(b_ih, on, f32) + ld_any(b_hh, on, f32);
  }
  for (int idx = tid; idx < 128 * 256; idx += nthr) {
    int j2 = idx >> 8, n = idx & 255;
    u16 lo = f2bf(ld_any(Hc_w, (size_t)n * H_ + 2 * j2, f32));
    u16 hi = f2bf(ld_any(Hc_w, (size_t)n * H_ + 2 * j2 + 1, f32));
    Hc_p[idx] = (unsigned int)lo | ((unsigned int)hi << 16);
  }
  for (int idx = tid; idx < 128 * 140; idx += nthr) {
    int j2 = idx / 140, v = idx - j2 * 140;
    u16 lo = f2bf(ld_any(Cd_w, (size_t)v * H_ + 2 * j2, f32));
    u16 hi = f2bf(ld_any(Cd_w, (size_t)v * H_ + 2 * j2 + 1, f32));
    Cd_p[idx] = (unsigned int)lo | ((unsigned int)hi << 16);
  }
  for (int n = tid; n < A_; n += nthr) hcb_f[n] = ld_any(Hc_b, n, f32);
  for (int n = tid; n < V_; n += nthr) cdb_f[n] = ld_any(Cd_b, n, f32);
}

// ---------------- phase 1: attn_img = img @ Ic_w^T + Ic_b (bf16 out) ---------
__global__ __launch_bounds__(256) void k_proj(const void* __restrict__ img,
                                              const void* __restrict__ Ic_w,
                                              const void* __restrict__ Ic_b,
                                              u16* __restrict__ attn_img,
                                              const int* __restrict__ flag) {
  __shared__ __align__(16) short As[128 * 32];
  __shared__ __align__(16) short Bs[128 * 32];
  const int f32 = *flag;
  const int tid = threadIdx.x;
  const int lane = tid & 63, w = tid >> 6;
  const int wg = blockIdx.x;
  const int m0 = ((wg & 7) + (wg >> 4) * 8) * 128;
  const int n0 = ((wg >> 3) & 1) * 128;
  f32x4 acc[4][4] = {};
  const int wm = w & 1, wn = w >> 1;
  const int fr = lane & 15, fq = lane >> 4;
  const int srow = tid >> 2, scol = (tid & 3) * 8;
  for (int kt = 0; kt < C_; kt += 32) {
    bf16x8 a0 = ld8_any(img, (size_t)(m0 + srow) * C_ + kt + scol, f32);
    bf16x8 a1 = ld8_any(img, (size_t)(m0 + srow + 64) * C_ + kt + scol, f32);
    bf16x8 b0 = ld8_any(Ic_w, (size_t)(n0 + srow) * C_ + kt + scol, f32);
    bf16x8 b1 = ld8_any(Ic_w, (size_t)(n0 + srow + 64) * C_ + kt + scol, f32);
    __syncthreads();
    *(bf16x8*)(As + tid * 8) = a0;
    *(bf16x8*)(As + (tid + 256) * 8) = a1;
    *(bf16x8*)(Bs + tid * 8) = b0;
    *(bf16x8*)(Bs + (tid + 256) * 8) = b1;
    __syncthreads();
    bf16x8 af[4], bfr[4];
    #pragma unroll
    for (int i = 0; i < 4; i++)
      af[i] = *(const bf16x8*)(As + (wm * 64 + i * 16 + fr) * 32 + fq * 8);
    #pragma unroll
    for (int j = 0; j < 4; j++)
      bfr[j] = *(const bf16x8*)(Bs + (wn * 64 + j * 16 + fr) * 32 + fq * 8);
    #pragma unroll
    for (int i = 0; i < 4; i++)
      #pragma unroll
      for (int j = 0; j < 4; j++)
        acc[i][j] = __builtin_amdgcn_mfma_f32_16x16x32_bf16(af[i], bfr[j], acc[i][j], 0, 0, 0);
  }
  #pragma unroll
  for (int i = 0; i < 4; i++) {
    #pragma unroll
    for (int j = 0; j < 4; j++) {
      const int col = n0 + wn * 64 + j * 16 + fr;
      const float bias = ld_any(Ic_b, col, f32);
      #pragma unroll
      for (int rr = 0; rr < 4; rr++) {
        const int row = m0 + wm * 64 + i * 16 + fq * 4 + rr;
        attn_img[(size_t)row * A_ + col] = f2bf(acc[i][j][rr] + bias);
      }
    }
  }
}

// ---------------- persistent recurrence: one block per batch, wave-specialized
__global__ __launch_bounds__(512, 2) void k_seq(
    const unsigned int* __restrict__ Hc_p, const float* __restrict__ hcb_f,
    const unsigned int* __restrict__ Cd_p, const float* __restrict__ cdb_f,
    const u16* __restrict__ W2, const float* __restrict__ bias_cat,
    const u16* __restrict__ attn_img, const void* __restrict__ targets,
    void* __restrict__ d_out, const int* __restrict__ flag) {
  __shared__ float h_s[H_];
  __shared__ float q_s[A_];
  __shared__ __align__(16) float inp_s[KC];   // [x(140) | ctx(256) | h(256) | 0pad]
  __shared__ __align__(16) float ctx_s[4][A_];
  __shared__ float red_l[4];
  __shared__ __align__(16) float gpart[1024]; // permuted gate accum, row jq=j*4+q
  const int f32 = *flag;
  const int b = blockIdx.x;
  const int tid = threadIdx.x;
  const int lane = tid & 63, w = tid >> 6;
  const uint4* wb = (const uint4*)W2;         // index (kk*4+blk)*256 + r

  if (tid < H_) h_s[tid] = 0.f;
  for (int i = tid; i < KC; i += 512) inp_s[i] = 0.f;
  if (tid < V_) inp_s[tid] = ld_any(targets, (size_t)b * T_ * V_ + tid, f32);
  float c_reg = 0.f;                          // thread tid<256 owns c[tid]
  float bias_b0 = 0.f, bias_b1 = 0.f, bias_b2 = 0.f, bias_b3 = 0.f;
  if (tid >= 256) {
    const int r = tid - 256;
    bias_b0 = bias_cat[r];       bias_b1 = bias_cat[256 + r];
    bias_b2 = bias_cat[512 + r]; bias_b3 = bias_cat[768 + r];
  }
  const float sc = 0.0625f * LOG2E;           // 1/sqrt(A) folded with log2(e)
  __syncthreads();

  for (int t = 0; t < T_; t++) {
    // ---- P1: q = h@Hc^T + b (tid<256) ; out_{t-1} = h@Cd^T + b (256..395) ---
    if (tid < A_) {
      float acc = hcb_f[tid];
      #pragma unroll 8
      for (int j2 = 0; j2 < H_ / 2; j2++) {
        const unsigned int u = Hc_p[j2 * 256 + tid];
        acc += bfu_lo(u) * h_s[2 * j2] + bfu_hi(u) * h_s[2 * j2 + 1];
      }
      q_s[tid] = acc;
    } else if (t > 0 && tid < A_ + V_) {
      const int v = tid - A_;
      float acc = cdb_f[v];
      #pragma unroll 8
      for (int j2 = 0; j2 < H_ / 2; j2++) {
        const unsigned int u = Cd_p[j2 * 140 + v];
        acc += bfu_lo(u) * h_s[2 * j2] + bfu_hi(u) * h_s[2 * j2 + 1];
      }
      const size_t oo = (size_t)b * T_ * V_ + (size_t)(t - 1) * V_ + v;
      if (f32) ((float*)d_out)[oo] = acc;
      else ((u16*)d_out)[oo] = f2bf(acc);
      inp_s[v] = acc;  // x_t = out_{t-1}
    }
    __syncthreads();  // barrier A

    // ---- P2: wave-specialized, no internal barriers ----
    if (w < 4) {
      // attention: 16 lanes/position; fixed-offset softmax (scores tiny by
      // construction: h tanh-bounded, weights ~N(0,0.02^2)); exp2(x-16)
      // cancels exactly after the /l normalize. Depth-2 prefetch pipeline.
      const int l16 = lane & 15, g = lane >> 4;
      float qr[16];
      #pragma unroll
      for (int e = 0; e < 8; e++) {
        qr[e] = q_s[l16 * 8 + e];
        qr[8 + e] = q_s[128 + l16 * 8 + e];
      }
      const uint4* ap = (const uint4*)(attn_img + (size_t)b * P_ * A_);
      const int pbase = w * 4 + g;
      uint4 cu0 = ap[(size_t)pbase * 32 + l16];
      uint4 cu1 = ap[(size_t)pbase * 32 + 16 + l16];
      uint4 nu0 = ap[(size_t)(pbase + 16) * 32 + l16];
      uint4 nu1 = ap[(size_t)(pbase + 16) * 32 + 16 + l16];
      float l_acc = 0.f;
      float cx[16] = {};
      for (int it = 0; it < 39; it++) {
        int pf = pbase + (it + 2) * 16;
        pf = (pf < P_) ? pf : (P_ - 1);
        const uint4 fu0 = ap[(size_t)pf * 32 + l16];
        const uint4 fu1 = ap[(size_t)pf * 32 + 16 + l16];
        const int p = pbase + it * 16;
        float v[16];
        v[0] = bfu_lo(cu0.x); v[1] = bfu_hi(cu0.x);
        v[2] = bfu_lo(cu0.y); v[3] = bfu_hi(cu0.y);
        v[4] = bfu_lo(cu0.z); v[5] = bfu_hi(cu0.z);
        v[6] = bfu_lo(cu0.w); v[7] = bfu_hi(cu0.w);
        v[8] = bfu_lo(cu1.x); v[9] = bfu_hi(cu1.x);
        v[10] = bfu_lo(cu1.y); v[11] = bfu_hi(cu1.y);
        v[12] = bfu_lo(cu1.z); v[13] = bfu_hi(cu1.z);
        v[14] = bfu_lo(cu1.w); v[15] = bfu_hi(cu1.w);
        float s0 = qr[0] * v[0] + qr[1] * v[1] + qr[2] * v[2] + qr[3] * v[3];
        float s1 = qr[4] * v[4] + qr[5] * v[5] + qr[6] * v[6] + qr[7] * v[7];
        float s2 = qr[8] * v[8] + qr[9] * v[9] + qr[10] * v[10] + qr[11] * v[11];
        float s3 = qr[12] * v[12] + qr[13] * v[13] + qr[14] * v[14] + qr[15] * v[15];
        float s = (s0 + s1) + (s2 + s3);
        s += __shfl_xor(s, 1); s += __shfl_xor(s, 2);
        s += __shfl_xor(s, 4); s += __shfl_xor(s, 8);
        const float sl = (p < P_) ? s * sc : -3.0e38f;
        const float es = __builtin_exp2f(sl - 16.f);
        l_acc += es;
        #pragma unroll
        for (int k = 0; k < 16; k++) cx[k] += es * v[k];
        cu0 = nu0; cu1 = nu1; nu0 = fu0; nu1 = fu1;
      }
      #pragma unroll
      for (int k = 0; k < 16; k++) {
        cx[k] += __shfl_xor(cx[k], 16);
        cx[k] += __shfl_xor(cx[k], 32);
      }
      l_acc += __shfl_xor(l_acc, 16);
      l_acc += __shfl_xor(l_acc, 32);
      if (g == 0) {
        #pragma unroll
        for (int e = 0; e < 8; e++) {
          ctx_s[w][l16 * 8 + e] = cx[e];
          ctx_s[w][128 + l16 * 8 + e] = cx[8 + e];
        }
        if (l16 == 0) red_l[w] = l_acc;
      }
    } else {
      // gates xh-partial: thread r owns rows {r, r+256, r+512, r+768},
      // chunks ck(i) = i + (i>=17)*33 -> {0..16} U {50..83}. Depth-1 prefetch.
      const int r = tid - 256;
      float g0 = bias_b0, g1 = bias_b1, g2 = bias_b2, g3 = bias_b3;
      int kk = 0;
      uint4 a0 = wb[(0 * 4 + 0) * 256 + r];
      uint4 a1 = wb[(0 * 4 + 1) * 256 + r];
      uint4 a2 = wb[(0 * 4 + 2) * 256 + r];
      uint4 a3 = wb[(0 * 4 + 3) * 256 + r];
      #pragma unroll 3
      for (int i = 0; i < 51; i++) {
        const int ni = (i + 1 < 51) ? i + 1 : 50;
        const int nk = ni + ((ni >= 17) ? 33 : 0);
        const uint4 b0v = wb[(nk * 4 + 0) * 256 + r];
        const uint4 b1v = wb[(nk * 4 + 1) * 256 + r];
        const uint4 b2v = wb[(nk * 4 + 2) * 256 + r];
        const uint4 b3v = wb[(nk * 4 + 3) * 256 + r];
        const float4 iA = *(const float4*)(inp_s + kk * 8);
        const float4 iB = *(const float4*)(inp_s + kk * 8 + 4);
        g0 += dot8(a0, iA, iB); g1 += dot8(a1, iA, iB);
        g2 += dot8(a2, iA, iB); g3 += dot8(a3, iA, iB);
        a0 = b0v; a1 = b1v; a2 = b2v; a3 = b3v; kk = nk;
      }
      gpart[r] = g0; gpart[256 + r] = g1;
      gpart[512 + r] = g2; gpart[768 + r] = g3;
    }
    __syncthreads();  // barrier B

    // ---- P3a: finalize ctx -> inp_s[140..395] ----
    if (tid < A_) {
      const float l = red_l[0] + red_l[1] + red_l[2] + red_l[3];
      const float cv = ctx_s[0][tid] + ctx_s[1][tid] + ctx_s[2][tid] + ctx_s[3][tid];
      inp_s[V_ + tid] = cv / l;
    }
    __syncthreads();  // barrier C

    // ---- P3b: gates ctx-part, thread owns rows {tid, tid+512}, chunks 17..49
    {
      float g0 = gpart[tid], g1 = gpart[tid + 512];
      const int blo = tid >> 8, rr = tid & 255;
      uint4 a0 = wb[(17 * 4 + blo) * 256 + rr];
      uint4 a1 = wb[(17 * 4 + 2 + blo) * 256 + rr];
      #pragma unroll 4
      for (int kk = 17; kk < 50; kk++) {
        const int nk = (kk + 1 < 50) ? kk + 1 : 49;
        const uint4 b0v = wb[(nk * 4 + blo) * 256 + rr];
        const uint4 b1v = wb[(nk * 4 + 2 + blo) * 256 + rr];
        const float4 iA = *(const float4*)(inp_s + kk * 8);
        const float4 iB = *(const float4*)(inp_s + kk * 8 + 4);
        g0 += dot8(a0, iA, iB);
        g1 += dot8(a1, iA, iB);
        a0 = b0v; a1 = b1v;
      }
      gpart[tid] = g0; gpart[tid + 512] = g1;
    }
    __syncthreads();  // barrier D

    // ---- cell: thread tid<256 owns hidden j = tid ----
    if (tid < H_) {
      const float4 g4 = *(const float4*)(gpart + 4 * tid);  // [i,f,g,o]
      const float is = sigf(g4.x), fs = sigf(g4.y);
      const float gt = tanhfast(g4.z), os = sigf(g4.w);
      const float cn = fs * c_reg + is * gt;
      const float h2 = os * tanhfast(cn);
      c_reg = cn;
      h_s[tid] = h2;
      inp_s[V_ + A_ + tid] = h2;
    }
    __syncthreads();  // barrier E
  }

  // ---- final out for t = T-1 ----
  if (tid < V_) {
    float acc = cdb_f[tid];
    #pragma unroll 8
    for (int j2 = 0; j2 < H_ / 2; j2++) {
      const unsigned int u = Cd_p[j2 * 140 + tid];
      acc += bfu_lo(u) * h_s[2 * j2] + bfu_hi(u) * h_s[2 * j2 + 1];
    }
    const size_t oo = (size_t)b * T_ * V_ + (size_t)(T_ - 1) * V_ + tid;
    if (f32) ((float*)d_out)[oo] = acc;
    else ((u16*)d_out)[oo] = f2bf(acc);
  }
}

extern "C" void kernel_launch(void* const* d_in, const int* in_sizes, int n_in,
                              void* d_out, int out_size, void* d_ws, size_t ws_size,
                              hipStream_t stream) {
  (void)in_sizes; (void)n_in; (void)out_size; (void)ws_size;
  const void* img  = d_in[0];
  const void* tgt  = d_in[1];
  const void* Ic_w = d_in[2];
  const void* Ic_b = d_in[3];
  const void* Hc_w = d_in[4];
  const void* Hc_b = d_in[5];
  const void* W_ih = d_in[6];
  const void* W_hh = d_in[7];
  const void* b_ih = d_in[8];
  const void* b_hh = d_in[9];
  const void* Cd_w = d_in[10];
  const void* Cd_b = d_in[11];

  char* ws = (char*)d_ws;
  size_t off = 0;
  auto alloc = [&](size_t bytes) -> void* {
    void* p = ws + off;
    off += (bytes + 255) & ~(size_t)255;
    return p;
  };
  u16*   attn_img = (u16*)alloc((size_t)B_ * P_ * A_ * 2);
  u16*   W2       = (u16*)alloc((size_t)1024 * KC * 2);
  float* bias_cat = (float*)alloc(1024 * 4);
  unsigned int* Hc_p = (unsigned int*)alloc((size_t)128 * 256 * 4);
  float* hcb_f    = (float*)alloc(A_ * 4);
  unsigned int* Cd_p = (unsigned int*)alloc((size_t)128 * 140 * 4);
  float* cdb_f    = (float*)alloc(V_ * 4);
  int*   flag     = (int*)alloc(256);

  k_detect<<<dim3(1), dim3(256), 0, stream>>>((const unsigned int*)img, flag);
  k_init<<<dim3(512), dim3(256), 0, stream>>>(W_ih, W_hh, b_ih, b_hh,
                                              Hc_w, Hc_b, Cd_w, Cd_b,
                                              W2, bias_cat,
                                              Hc_p, hcb_f, Cd_p, cdb_f, flag);
  k_proj<<<dim3(2480), dim3(256), 0, stream>>>(img, Ic_w, Ic_b, attn_img, flag);
  k_seq<<<dim3(B_), dim3(512), 0, stream>>>(Hc_p, hcb_f, Cd_p, cdb_f,
                                            W2, bias_cat, attn_img, tgt, d_out, flag);
}